// Round 8
// baseline (346.613 us; speedup 1.0000x reference)
//
#include <hip/hip_runtime.h>

#define C_N   512
#define E_N   261632

typedef _Float16 f16;
typedef _Float16 f16x8_t __attribute__((ext_vector_type(8)));
typedef float    f32x16_t __attribute__((ext_vector_type(16)));

// ---------------- fused prep ----------------
// [0,256): SA/RB  [256,384): W2 pack  [384,448): hist  [448,512): Wo1 pack
// [512,640): Wo2 pack  [640,704): Wo3 pack
__global__ __launch_bounds__(256) void k_prep(const float* __restrict__ inputs,
    const float* __restrict__ W1, const float* __restrict__ b1,
    const float* __restrict__ W2, const int* __restrict__ rec,
    const float* __restrict__ Wo1, const float* __restrict__ Wo2, const float* __restrict__ Wo3,
    f16* __restrict__ SA, f16* __restrict__ RB, f16* __restrict__ W2p,
    f16* __restrict__ Wo1p, f16* __restrict__ Wo2p, f16* __restrict__ Wo3p,
    int* __restrict__ hist_part)
{
  int bid = blockIdx.x;
  if (bid < 256) {
    int t  = bid >> 7;
    int c0 = (bid & 127) * 4;
    __shared__ float xs[4][256];
    for (int i = threadIdx.x; i < 1024; i += 256)
      xs[i >> 8][i & 255] = inputs[(size_t)(c0 + (i >> 8)) * 256 + (i & 255)];
    __syncthreads();
    const float* W1t = W1 + (size_t)t * 512 * 512;
    int h0 = threadIdx.x;
    float sa[2][4] = {{0.f}}, rbv[2][4] = {{0.f}};
    #pragma unroll 4
    for (int d = 0; d < 256; d++) {
      float wt0 = W1t[d * 512 + h0];
      float wt1 = W1t[d * 512 + h0 + 256];
      float wb0 = W1t[(256 + d) * 512 + h0];
      float wb1 = W1t[(256 + d) * 512 + h0 + 256];
      #pragma unroll
      for (int r = 0; r < 4; r++) {
        float x = xs[r][d];
        sa[0][r]  += x * wt0; sa[1][r]  += x * wt1;
        rbv[0][r] += x * wb0; rbv[1][r] += x * wb1;
      }
    }
    #pragma unroll
    for (int hh = 0; hh < 2; hh++) {
      int h = h0 + hh * 256;
      float bb = b1[t * 512 + h];
      #pragma unroll
      for (int r = 0; r < 4; r++) {
        SA[((size_t)(t * 512 + c0 + r)) * 512 + h] = (f16)sa[hh][r];
        RB[((size_t)(t * 512 + c0 + r)) * 512 + h] = (f16)(rbv[hh][r] + bb);
      }
    }
  } else if (bid < 384) {
    int gid  = (bid - 256) * 256 + threadIdx.x;   // 0..32767
    int lane = gid & 63;
    int ct   = (gid >> 6) & 7;
    int kc   = (gid >> 9) & 31;
    int t    = gid >> 14;
    int n    = ct * 32 + (lane & 31);
    int k0   = kc * 16 + (lane >> 5) * 8;
    const float* src = W2 + (size_t)t * 512 * 256;
    f16x8_t v;
    #pragma unroll
    for (int j = 0; j < 8; j++) v[j] = (f16)src[(size_t)(k0 + j) * 256 + n];
    *(f16x8_t*)(W2p + (size_t)gid * 8) = v;
  } else if (bid < 448) {
    int hb = bid - 384;
    __shared__ int lh[512];
    for (int i = threadIdx.x; i < 512; i += 256) lh[i] = 0;
    __syncthreads();
    int e0 = hb * (E_N / 64);
    for (int i = threadIdx.x; i < E_N / 64; i += 256)
      atomicAdd(&lh[rec[e0 + i]], 1);
    __syncthreads();
    for (int i = threadIdx.x; i < 512; i += 256)
      hist_part[hb * 512 + i] = lh[i];
  } else if (bid < 512) {
    int gid  = (bid - 448) * 256 + threadIdx.x;   // 0..16383
    int lane = gid & 63;
    int ct   = (gid >> 6) & 15;
    int kc   = gid >> 10;                          // 0..15
    int n    = ct * 32 + (lane & 31);
    int k0   = kc * 16 + (lane >> 5) * 8;
    f16x8_t v;
    #pragma unroll
    for (int j = 0; j < 8; j++) v[j] = (f16)Wo1[(size_t)(k0 + j) * 512 + n];
    *(f16x8_t*)(Wo1p + (size_t)gid * 8) = v;
  } else if (bid < 640) {
    int gid  = (bid - 512) * 256 + threadIdx.x;   // 0..32767
    int lane = gid & 63;
    int ct   = (gid >> 6) & 15;
    int kc   = gid >> 10;                          // 0..31
    int n    = ct * 32 + (lane & 31);
    int k0   = kc * 16 + (lane >> 5) * 8;
    f16x8_t v;
    #pragma unroll
    for (int j = 0; j < 8; j++) v[j] = (f16)Wo2[(size_t)(k0 + j) * 512 + n];
    *(f16x8_t*)(Wo2p + (size_t)gid * 8) = v;
  } else {
    int gid  = (bid - 640) * 256 + threadIdx.x;   // 0..16383
    int lane = gid & 63;
    int ct   = (gid >> 6) & 7;
    int kc   = gid >> 9;                           // 0..31
    int n    = ct * 32 + (lane & 31);
    int k0   = kc * 16 + (lane >> 5) * 8;
    f16x8_t v;
    #pragma unroll
    for (int j = 0; j < 8; j++) v[j] = (f16)Wo3[(size_t)(k0 + j) * 256 + n];
    *(f16x8_t*)(Wo3p + (size_t)gid * 8) = v;
  }
}

// ---------------- scan ----------------
__global__ void k_scan(const int* __restrict__ hist_part, int* __restrict__ seg,
                       int* __restrict__ base)
{
  __shared__ int s[512];
  int tid = threadIdx.x;
  int tot = 0;
  #pragma unroll 8
  for (int b = 0; b < 64; b++) tot += hist_part[b * 512 + tid];
  s[tid] = tot;
  __syncthreads();
  for (int off = 1; off < 512; off <<= 1) {
    int v = (tid >= off) ? s[tid - off] : 0;
    __syncthreads();
    s[tid] += v;
    __syncthreads();
  }
  int excl = s[tid] - tot;
  seg[tid] = excl;
  if (tid == 0) seg[512] = E_N;
  int run = excl;
  for (int b = 0; b < 64; b++) {
    base[b * 512 + tid] = run;
    run += hist_part[b * 512 + tid];
  }
}

// ---------------- scatter ----------------
__global__ __launch_bounds__(1024) void k_scatter3(const int* __restrict__ rec,
    const int* __restrict__ send, const float* __restrict__ rel,
    const int* __restrict__ base, int* __restrict__ ssend, float2* __restrict__ srel)
{
  __shared__ int lh[512];
  __shared__ int lb[512];
  int b = blockIdx.x;
  int e0 = b * (E_N / 64);
  for (int i = threadIdx.x; i < 512; i += 1024) { lh[i] = 0; lb[i] = base[b * 512 + i]; }
  __syncthreads();
  for (int i = threadIdx.x; i < E_N / 64; i += 1024) {
    int e = e0 + i;
    int r = rec[e];
    int p = lb[r] + atomicAdd(&lh[r], 1);
    ssend[p] = send[e];
    srel[p]  = make_float2(rel[2 * (size_t)e], rel[2 * (size_t)e + 1]);
  }
}

// ---------------- K5: edge MLP + aggregation (128-edge tiles, 1 block/CU) ----------------
#define H1S 520

__global__ __launch_bounds__(512, 2) void k_edges(
    const f16* __restrict__ SA, const f16* __restrict__ RB,
    const f16* __restrict__ W2p, const float* __restrict__ b2,
    const int* __restrict__ ssend, const float2* __restrict__ srel,
    const int* __restrict__ seg, float* __restrict__ agg)
{
  __shared__ f16   h1[128 * H1S];     // 133120 B
  __shared__ f16   rbs[2][512];       // 2048 B
  __shared__ float b2s[2][256];       // 2048 B
  __shared__ float aggL[256];         // 1024 B
  __shared__ float relv2[2][128][2];  // 2048 B
  __shared__ int   sends2[2][128];    // 1024 B  (total ~141 KB -> 1 block/CU)

  int c    = blockIdx.x;
  int tid  = threadIdx.x;             // 0..511
  int lane = tid & 63;
  int w    = tid >> 6;                // wave 0..7 -> col tile w (32 cols)
  int hlf  = lane >> 5;
  int l31  = lane & 31;
  int q    = tid & 63;                // 16B chunk in a 512-f16 row
  int rb0  = tid >> 6;                // rows rb0 + 8j, j=0..15

  if (tid < 128) {
    int t = tid >> 6, qq = tid & 63;
    *(f16x8_t*)&rbs[t][qq * 8] = *(const f16x8_t*)&RB[((size_t)(t * 512 + c)) * 512 + qq * 8];
  }
  if (tid < 256) aggL[tid] = 0.0f;
  { int t = (tid >> 8) & 1, col = tid & 255; b2s[t][col] = b2[t * 256 + col]; }

  int s0 = seg[c], s1 = seg[c + 1];
  int nt = (s1 - s0 + 127) >> 7;      // tiles of 128 edges

  if (nt > 0 && tid < 128) {
    int pos = s0 + tid;
    if (pos < s1) {
      sends2[0][tid] = ssend[pos];
      float2 rr = srel[pos];
      relv2[0][tid][0] = rr.x;
      relv2[0][tid][1] = rr.y;
    } else {
      sends2[0][tid] = 0; relv2[0][tid][0] = 0.f; relv2[0][tid][1] = 0.f;
    }
  }
  __syncthreads();

  f16x8_t g[16];
  const f16x8_t* SAc = (const f16x8_t*)SA;
  const f16x8_t* Bp  = (const f16x8_t*)W2p;

  if (nt > 0) {
    #pragma unroll
    for (int j = 0; j < 16; j++)
      g[j] = SAc[(size_t)sends2[0][rb0 + 8 * j] * 64 + q];
  }

  for (int ph = 0; ph < 2 * nt; ph++) {
    int ti  = ph >> 1;
    int t   = ph & 1;
    int cb  = ti & 1;
    int nb  = cb ^ 1;
    bool more = (ti + 1 < nt);

    // ---- build h1[128][512] = relu(SA + RB) from prefetched g ----
    {
      f16x8_t rbq = *(const f16x8_t*)&rbs[t][q * 8];
      #pragma unroll
      for (int j = 0; j < 16; j++) {
        int row = rb0 + 8 * j;
        f16x8_t hv;
        #pragma unroll
        for (int e = 0; e < 8; e++) {
          f16 v = (f16)(g[j][e] + rbq[e]);
          hv[e] = (v > (f16)0.0f) ? v : (f16)0.0f;
        }
        *(f16x8_t*)&h1[row * H1S + q * 8] = hv;
      }
    }
    __syncthreads();

    if (t == 0 && more && tid < 128) {
      int pos = s0 + (ti + 1) * 128 + tid;
      if (pos < s1) {
        sends2[nb][tid] = ssend[pos];
        float2 rr = srel[pos];
        relv2[nb][tid][0] = rr.x;
        relv2[nb][tid][1] = rr.y;
      } else {
        sends2[nb][tid] = 0; relv2[nb][tid][0] = 0.f; relv2[nb][tid][1] = 0.f;
      }
    }

    // ---- GEMM: msg[128,256] = h1 @ W2[t]; wave = 4 row-tiles x 1 col-tile ----
    f32x16_t acc[4];
    #pragma unroll
    for (int rt = 0; rt < 4; rt++)
      #pragma unroll
      for (int r = 0; r < 16; r++) acc[rt][r] = 0.f;

    f16x8_t bb[2];
    bb[0] = Bp[(size_t)(((t * 32 + 0) * 8 + w) * 64 + lane)];
    bb[1] = Bp[(size_t)(((t * 32 + 1) * 8 + w) * 64 + lane)];

    // cross-phase gather after initial B loads (FIFO: stays in flight)
    if (t == 0) {
      #pragma unroll
      for (int j = 0; j < 16; j++)
        g[j] = SAc[(size_t)(512 + sends2[cb][rb0 + 8 * j]) * 64 + q];
    } else if (more) {
      #pragma unroll
      for (int j = 0; j < 16; j++)
        g[j] = SAc[(size_t)sends2[nb][rb0 + 8 * j] * 64 + q];
    }

    for (int kc = 0; kc < 32; kc++) {
      int pb = kc & 1;
      #pragma unroll
      for (int rt = 0; rt < 4; rt++) {
        f16x8_t af = *(const f16x8_t*)&h1[(rt * 32 + l31) * H1S + kc * 16 + hlf * 8];
        acc[rt] = __builtin_amdgcn_mfma_f32_32x32x16_f16(af, bb[pb], acc[rt], 0, 0, 0);
      }
      if (kc + 2 < 32)
        bb[pb] = Bp[(size_t)(((t * 32 + kc + 2) * 8 + w) * 64 + lane)];
    }

    // ---- epilogue ----
    {
      int col = w * 32 + l31;
      float b2c = b2s[t][col];
      float csum = 0.0f;
      #pragma unroll
      for (int rt = 0; rt < 4; rt++)
        #pragma unroll
        for (int r = 0; r < 16; r++) {
          int row = rt * 32 + (r & 3) + 8 * (r >> 2) + 4 * hlf;
          float v = fmaxf(acc[rt][r] + b2c, 0.0f);
          csum += v * relv2[cb][row][t];
        }
      csum += __shfl_xor(csum, 32, 64);
      if (hlf == 0) aggL[col] += csum;   // waves own disjoint cols
    }
    __syncthreads();
  }

  if (tid < 256) agg[(size_t)c * 256 + tid] = aggL[tid];
}

// ---------------- output MLP: three MFMA layer kernels ----------------
__global__ __launch_bounds__(256) void k_omlp1(const float* __restrict__ agg,
    const f16* __restrict__ Wo1p, const float* __restrict__ bo1, f16* __restrict__ h1o)
{
  int tid = threadIdx.x, lane = tid & 63, w = tid >> 6;
  int hlf = lane >> 5, l31 = lane & 31;
  int br = blockIdx.x, bc = blockIdx.y;
  f32x16_t acc[2][2];
  #pragma unroll
  for (int rt = 0; rt < 2; rt++)
    #pragma unroll
    for (int ctl = 0; ctl < 2; ctl++)
      #pragma unroll
      for (int r = 0; r < 16; r++) acc[rt][ctl][r] = 0.f;
  for (int kc = 0; kc < 16; kc++) {
    f16x8_t af[2];
    #pragma unroll
    for (int rt = 0; rt < 2; rt++) {
      const float4* p = (const float4*)&agg[(size_t)(br * 64 + rt * 32 + l31) * 256 + kc * 16 + hlf * 8];
      float4 u0 = p[0], u1 = p[1];
      af[rt] = (f16x8_t){(f16)u0.x, (f16)u0.y, (f16)u0.z, (f16)u0.w,
                         (f16)u1.x, (f16)u1.y, (f16)u1.z, (f16)u1.w};
    }
    #pragma unroll
    for (int ctl = 0; ctl < 2; ctl++) {
      f16x8_t bfr = *(const f16x8_t*)&Wo1p[((size_t)(kc * 16 + bc * 8 + 2 * w + ctl) * 64 + lane) * 8];
      #pragma unroll
      for (int rt = 0; rt < 2; rt++)
        acc[rt][ctl] = __builtin_amdgcn_mfma_f32_32x32x16_f16(af[rt], bfr, acc[rt][ctl], 0, 0, 0);
    }
  }
  #pragma unroll
  for (int ctl = 0; ctl < 2; ctl++) {
    int col = bc * 256 + (2 * w + ctl) * 32 + l31;
    float bias = bo1[col];
    #pragma unroll
    for (int rt = 0; rt < 2; rt++)
      #pragma unroll
      for (int r = 0; r < 16; r++) {
        int row = br * 64 + rt * 32 + (r & 3) + 8 * (r >> 2) + 4 * hlf;
        h1o[(size_t)row * 512 + col] = (f16)fmaxf(acc[rt][ctl][r] + bias, 0.f);
      }
  }
}

__global__ __launch_bounds__(256) void k_omlp2(const f16* __restrict__ h1o,
    const f16* __restrict__ Wo2p, const float* __restrict__ bo2, f16* __restrict__ h2o)
{
  int tid = threadIdx.x, lane = tid & 63, w = tid >> 6;
  int hlf = lane >> 5, l31 = lane & 31;
  int br = blockIdx.x, bc = blockIdx.y;
  f32x16_t acc[2][2];
  #pragma unroll
  for (int rt = 0; rt < 2; rt++)
    #pragma unroll
    for (int ctl = 0; ctl < 2; ctl++)
      #pragma unroll
      for (int r = 0; r < 16; r++) acc[rt][ctl][r] = 0.f;
  for (int kc = 0; kc < 32; kc++) {
    f16x8_t af[2];
    #pragma unroll
    for (int rt = 0; rt < 2; rt++)
      af[rt] = *(const f16x8_t*)&h1o[(size_t)(br * 64 + rt * 32 + l31) * 512 + kc * 16 + hlf * 8];
    #pragma unroll
    for (int ctl = 0; ctl < 2; ctl++) {
      f16x8_t bfr = *(const f16x8_t*)&Wo2p[((size_t)(kc * 16 + bc * 8 + 2 * w + ctl) * 64 + lane) * 8];
      #pragma unroll
      for (int rt = 0; rt < 2; rt++)
        acc[rt][ctl] = __builtin_amdgcn_mfma_f32_32x32x16_f16(af[rt], bfr, acc[rt][ctl], 0, 0, 0);
    }
  }
  #pragma unroll
  for (int ctl = 0; ctl < 2; ctl++) {
    int col = bc * 256 + (2 * w + ctl) * 32 + l31;
    float bias = bo2[col];
    #pragma unroll
    for (int rt = 0; rt < 2; rt++)
      #pragma unroll
      for (int r = 0; r < 16; r++) {
        int row = br * 64 + rt * 32 + (r & 3) + 8 * (r >> 2) + 4 * hlf;
        h2o[(size_t)row * 512 + col] = (f16)fmaxf(acc[rt][ctl][r] + bias, 0.f);
      }
  }
}

__global__ __launch_bounds__(256) void k_omlp3(const f16* __restrict__ h2o,
    const f16* __restrict__ Wo3p, const float* __restrict__ bo3, float* __restrict__ out)
{
  int tid = threadIdx.x, lane = tid & 63, w = tid >> 6;
  int hlf = lane >> 5, l31 = lane & 31;
  int br = blockIdx.x;
  f32x16_t acc[2][2];
  #pragma unroll
  for (int rt = 0; rt < 2; rt++)
    #pragma unroll
    for (int ctl = 0; ctl < 2; ctl++)
      #pragma unroll
      for (int r = 0; r < 16; r++) acc[rt][ctl][r] = 0.f;
  for (int kc = 0; kc < 32; kc++) {
    f16x8_t af[2];
    #pragma unroll
    for (int rt = 0; rt < 2; rt++)
      af[rt] = *(const f16x8_t*)&h2o[(size_t)(br * 64 + rt * 32 + l31) * 512 + kc * 16 + hlf * 8];
    #pragma unroll
    for (int ctl = 0; ctl < 2; ctl++) {
      f16x8_t bfr = *(const f16x8_t*)&Wo3p[((size_t)(kc * 8 + 2 * w + ctl) * 64 + lane) * 8];
      #pragma unroll
      for (int rt = 0; rt < 2; rt++)
        acc[rt][ctl] = __builtin_amdgcn_mfma_f32_32x32x16_f16(af[rt], bfr, acc[rt][ctl], 0, 0, 0);
    }
  }
  #pragma unroll
  for (int ctl = 0; ctl < 2; ctl++) {
    int col = (2 * w + ctl) * 32 + l31;
    float bias = bo3[col];
    #pragma unroll
    for (int rt = 0; rt < 2; rt++)
      #pragma unroll
      for (int r = 0; r < 16; r++) {
        int row = br * 64 + rt * 32 + (r & 3) + 8 * (r >> 2) + 4 * hlf;
        out[(size_t)row * 256 + col] = acc[rt][ctl][r] + bias;
      }
  }
}

// ---------------- launcher ----------------
extern "C" void kernel_launch(void* const* d_in, const int* in_sizes, int n_in,
                              void* d_out, int out_size, void* d_ws, size_t ws_size,
                              hipStream_t stream)
{
  (void)in_sizes; (void)n_in; (void)out_size; (void)ws_size;
  const float* inputs = (const float*)d_in[0];
  const float* rel    = (const float*)d_in[1];
  const float* W1     = (const float*)d_in[2];
  const float* b1     = (const float*)d_in[3];
  const float* W2     = (const float*)d_in[4];
  const float* b2     = (const float*)d_in[5];
  const float* Wo1    = (const float*)d_in[6];
  const float* bo1    = (const float*)d_in[7];
  const float* Wo2    = (const float*)d_in[8];
  const float* bo2    = (const float*)d_in[9];
  const float* Wo3    = (const float*)d_in[10];
  const float* bo3    = (const float*)d_in[11];
  const int* send_idx = (const int*)d_in[12];
  const int* rec_idx  = (const int*)d_in[13];
  float* out = (float*)d_out;

  char* ws = (char*)d_ws;
  f16*    SA        = (f16*)   (ws);                              // 1 MB
  f16*    RB        = (f16*)   (ws + (1u << 20));                 // 1 MB
  f16*    W2p       = (f16*)   (ws + (2u << 20));                 // 512 KB
  float*  agg       = (float*) (ws + (2560u << 10));              // 512 KB
  int*    hist_part = (int*)   (ws + (3u << 20));                 // 128 KB
  int*    seg       = (int*)   (ws + (3u << 20) + (128u << 10));  // 4 KB
  int*    base      = (int*)   (ws + (3u << 20) + (132u << 10));  // 128 KB
  int*    ssend     = (int*)   (ws + (3584u << 10));              // 1 MB
  float2* srel      = (float2*)(ws + (4608u << 10));              // 2 MB
  f16*    Wo1p      = (f16*)   (ws + (6656u << 10));              // 256 KB
  f16*    Wo2p      = (f16*)   (ws + (6912u << 10));              // 512 KB
  f16*    Wo3p      = (f16*)   (ws + (7424u << 10));              // 256 KB
  f16*    h1o       = (f16*)   (ws + (7680u << 10));              // 512 KB
  f16*    h2o       = (f16*)   (ws + (8192u << 10));              // 512 KB (total 8.5 MB)

  k_prep    <<<dim3(704), dim3(256),  0, stream>>>(inputs, W1, b1, W2, rec_idx,
                                                   Wo1, Wo2, Wo3,
                                                   SA, RB, W2p, Wo1p, Wo2p, Wo3p, hist_part);
  k_scan    <<<dim3(1),   dim3(512),  0, stream>>>(hist_part, seg, base);
  k_scatter3<<<dim3(64),  dim3(1024), 0, stream>>>(rec_idx, send_idx, rel, base, ssend, srel);
  k_edges   <<<dim3(512), dim3(512),  0, stream>>>(SA, RB, W2p, b2, ssend, srel, seg, agg);
  k_omlp1   <<<dim3(8,2), dim3(256),  0, stream>>>(agg, Wo1p, bo1, h1o);
  k_omlp2   <<<dim3(8,2), dim3(256),  0, stream>>>(h1o, Wo2p, bo2, h2o);
  k_omlp3   <<<dim3(8),   dim3(256),  0, stream>>>(h2o, Wo3p, bo3, out);
}

// Round 9
// 332.058 us; speedup vs baseline: 1.0438x; 1.0438x over previous
//
#include <hip/hip_runtime.h>

#define C_N   512
#define E_N   261632

typedef _Float16 f16;
typedef _Float16 f16x8_t __attribute__((ext_vector_type(8)));
typedef float    f32x16_t __attribute__((ext_vector_type(16)));

// ---------------- fused prep ----------------
// [0,256): SA/RB  [256,384): W2 pack  [384,448): hist  [448,512): Wo1 pack
// [512,640): Wo2 pack  [640,704): Wo3 pack
__global__ __launch_bounds__(256) void k_prep(const float* __restrict__ inputs,
    const float* __restrict__ W1, const float* __restrict__ b1,
    const float* __restrict__ W2, const int* __restrict__ rec,
    const float* __restrict__ Wo1, const float* __restrict__ Wo2, const float* __restrict__ Wo3,
    f16* __restrict__ SA, f16* __restrict__ RB, f16* __restrict__ W2p,
    f16* __restrict__ Wo1p, f16* __restrict__ Wo2p, f16* __restrict__ Wo3p,
    int* __restrict__ hist_part)
{
  int bid = blockIdx.x;
  if (bid < 256) {
    int t  = bid >> 7;
    int c0 = (bid & 127) * 4;
    __shared__ float xs[4][256];
    for (int i = threadIdx.x; i < 1024; i += 256)
      xs[i >> 8][i & 255] = inputs[(size_t)(c0 + (i >> 8)) * 256 + (i & 255)];
    __syncthreads();
    const float* W1t = W1 + (size_t)t * 512 * 512;
    int h0 = threadIdx.x;
    float sa[2][4] = {{0.f}}, rbv[2][4] = {{0.f}};
    #pragma unroll 4
    for (int d = 0; d < 256; d++) {
      float wt0 = W1t[d * 512 + h0];
      float wt1 = W1t[d * 512 + h0 + 256];
      float wb0 = W1t[(256 + d) * 512 + h0];
      float wb1 = W1t[(256 + d) * 512 + h0 + 256];
      #pragma unroll
      for (int r = 0; r < 4; r++) {
        float x = xs[r][d];
        sa[0][r]  += x * wt0; sa[1][r]  += x * wt1;
        rbv[0][r] += x * wb0; rbv[1][r] += x * wb1;
      }
    }
    #pragma unroll
    for (int hh = 0; hh < 2; hh++) {
      int h = h0 + hh * 256;
      float bb = b1[t * 512 + h];
      #pragma unroll
      for (int r = 0; r < 4; r++) {
        SA[((size_t)(t * 512 + c0 + r)) * 512 + h] = (f16)sa[hh][r];
        RB[((size_t)(t * 512 + c0 + r)) * 512 + h] = (f16)(rbv[hh][r] + bb);
      }
    }
  } else if (bid < 384) {
    int gid  = (bid - 256) * 256 + threadIdx.x;   // 0..32767
    int lane = gid & 63;
    int ct   = (gid >> 6) & 7;
    int kc   = (gid >> 9) & 31;
    int t    = gid >> 14;
    int n    = ct * 32 + (lane & 31);
    int k0   = kc * 16 + (lane >> 5) * 8;
    const float* src = W2 + (size_t)t * 512 * 256;
    f16x8_t v;
    #pragma unroll
    for (int j = 0; j < 8; j++) v[j] = (f16)src[(size_t)(k0 + j) * 256 + n];
    *(f16x8_t*)(W2p + (size_t)gid * 8) = v;
  } else if (bid < 448) {
    int hb = bid - 384;
    __shared__ int lh[512];
    for (int i = threadIdx.x; i < 512; i += 256) lh[i] = 0;
    __syncthreads();
    int e0 = hb * (E_N / 64);
    for (int i = threadIdx.x; i < E_N / 64; i += 256)
      atomicAdd(&lh[rec[e0 + i]], 1);
    __syncthreads();
    for (int i = threadIdx.x; i < 512; i += 256)
      hist_part[hb * 512 + i] = lh[i];
  } else if (bid < 512) {
    int gid  = (bid - 448) * 256 + threadIdx.x;   // 0..16383
    int lane = gid & 63;
    int ct   = (gid >> 6) & 15;
    int kc   = gid >> 10;                          // 0..15
    int n    = ct * 32 + (lane & 31);
    int k0   = kc * 16 + (lane >> 5) * 8;
    f16x8_t v;
    #pragma unroll
    for (int j = 0; j < 8; j++) v[j] = (f16)Wo1[(size_t)(k0 + j) * 512 + n];
    *(f16x8_t*)(Wo1p + (size_t)gid * 8) = v;
  } else if (bid < 640) {
    int gid  = (bid - 512) * 256 + threadIdx.x;   // 0..32767
    int lane = gid & 63;
    int ct   = (gid >> 6) & 15;
    int kc   = gid >> 10;                          // 0..31
    int n    = ct * 32 + (lane & 31);
    int k0   = kc * 16 + (lane >> 5) * 8;
    f16x8_t v;
    #pragma unroll
    for (int j = 0; j < 8; j++) v[j] = (f16)Wo2[(size_t)(k0 + j) * 512 + n];
    *(f16x8_t*)(Wo2p + (size_t)gid * 8) = v;
  } else {
    int gid  = (bid - 640) * 256 + threadIdx.x;   // 0..16383
    int lane = gid & 63;
    int ct   = (gid >> 6) & 7;
    int kc   = gid >> 9;                           // 0..31
    int n    = ct * 32 + (lane & 31);
    int k0   = kc * 16 + (lane >> 5) * 8;
    f16x8_t v;
    #pragma unroll
    for (int j = 0; j < 8; j++) v[j] = (f16)Wo3[(size_t)(k0 + j) * 256 + n];
    *(f16x8_t*)(Wo3p + (size_t)gid * 8) = v;
  }
}

// ---------------- scan ----------------
__global__ void k_scan(const int* __restrict__ hist_part, int* __restrict__ seg,
                       int* __restrict__ base)
{
  __shared__ int s[512];
  int tid = threadIdx.x;
  int tot = 0;
  #pragma unroll 8
  for (int b = 0; b < 64; b++) tot += hist_part[b * 512 + tid];
  s[tid] = tot;
  __syncthreads();
  for (int off = 1; off < 512; off <<= 1) {
    int v = (tid >= off) ? s[tid - off] : 0;
    __syncthreads();
    s[tid] += v;
    __syncthreads();
  }
  int excl = s[tid] - tot;
  seg[tid] = excl;
  if (tid == 0) seg[512] = E_N;
  int run = excl;
  for (int b = 0; b < 64; b++) {
    base[b * 512 + tid] = run;
    run += hist_part[b * 512 + tid];
  }
}

// ---------------- scatter ----------------
__global__ __launch_bounds__(1024) void k_scatter3(const int* __restrict__ rec,
    const int* __restrict__ send, const float* __restrict__ rel,
    const int* __restrict__ base, int* __restrict__ ssend, float2* __restrict__ srel)
{
  __shared__ int lh[512];
  __shared__ int lb[512];
  int b = blockIdx.x;
  int e0 = b * (E_N / 64);
  for (int i = threadIdx.x; i < 512; i += 1024) { lh[i] = 0; lb[i] = base[b * 512 + i]; }
  __syncthreads();
  for (int i = threadIdx.x; i < E_N / 64; i += 1024) {
    int e = e0 + i;
    int r = rec[e];
    int p = lb[r] + atomicAdd(&lh[r], 1);
    ssend[p] = send[e];
    srel[p]  = make_float2(rel[2 * (size_t)e], rel[2 * (size_t)e + 1]);
  }
}

// ---------------- K5: edge MLP + aggregation ----------------
// 128-edge tiles, K split into two 256-wide halves so LDS stays ~74 KB
// -> 2 blocks/CU.  Wave = 4 row-tiles x 1 col-tile of 32x32 MFMA.
#define H1S2 264   // f16 per half-row: 256 + 8 pad (row stride 4 banks mod 32)

__global__ __launch_bounds__(512, 4) void k_edges(
    const f16* __restrict__ SA, const f16* __restrict__ RB,
    const f16* __restrict__ W2p, const float* __restrict__ b2,
    const int* __restrict__ ssend, const float2* __restrict__ srel,
    const int* __restrict__ seg, float* __restrict__ agg)
{
  __shared__ f16   h1[128 * H1S2];    // 67584 B
  __shared__ f16   rbs[2][512];       // 2048 B
  __shared__ float b2s[2][256];       // 2048 B
  __shared__ float aggL[256];         // 1024 B
  __shared__ float relv2[2][128][2];  // 2048 B
  __shared__ int   sends2[2][128];    // 1024 B  (total ~75.8 KB -> 2 blocks/CU)

  int c    = blockIdx.x;
  int tid  = threadIdx.x;             // 0..511
  int lane = tid & 63;
  int w    = tid >> 6;                // wave 0..7 -> col tile w (32 cols)
  int hlf  = lane >> 5;
  int l31  = lane & 31;
  int q5   = tid & 31;                // 16B chunk within a 256-f16 half-row
  int rb0  = tid >> 5;                // 0..15; rows rb0 + 16j, j=0..7

  if (tid < 128) {
    int t = tid >> 6, qq = tid & 63;
    *(f16x8_t*)&rbs[t][qq * 8] = *(const f16x8_t*)&RB[((size_t)(t * 512 + c)) * 512 + qq * 8];
  }
  if (tid < 256) aggL[tid] = 0.0f;
  { int t = (tid >> 8) & 1, col = tid & 255; b2s[t][col] = b2[t * 256 + col]; }

  int s0 = seg[c], s1 = seg[c + 1];
  int nt = (s1 - s0 + 127) >> 7;      // tiles of 128 edges

  if (nt > 0 && tid < 128) {
    int pos = s0 + tid;
    if (pos < s1) {
      sends2[0][tid] = ssend[pos];
      float2 rr = srel[pos];
      relv2[0][tid][0] = rr.x;
      relv2[0][tid][1] = rr.y;
    } else {
      sends2[0][tid] = 0; relv2[0][tid][0] = 0.f; relv2[0][tid][1] = 0.f;
    }
  }
  __syncthreads();

  f16x8_t g[8];
  const f16x8_t* SAc = (const f16x8_t*)SA;   // row r of type t at chunk (t*512+r)*64
  const f16x8_t* Bp  = (const f16x8_t*)W2p;
  f32x16_t acc[4];

  if (nt > 0) {
    #pragma unroll
    for (int j = 0; j < 8; j++)
      g[j] = SAc[(size_t)sends2[0][rb0 + 16 * j] * 64 + q5];   // (t=0, kh=0)
  }

  for (int ph = 0; ph < 4 * nt; ph++) {
    int ti  = ph >> 2;
    int t   = (ph >> 1) & 1;
    int kh  = ph & 1;
    int cb  = ti & 1;
    int nb  = cb ^ 1;
    bool more = (ti + 1 < nt);

    // ---- build h1 half-slice = relu(SA + RB) from prefetched g ----
    {
      f16x8_t rbq = *(const f16x8_t*)&rbs[t][(kh * 32 + q5) * 8];
      #pragma unroll
      for (int j = 0; j < 8; j++) {
        int row = rb0 + 16 * j;
        f16x8_t hv;
        #pragma unroll
        for (int e = 0; e < 8; e++) {
          f16 v = (f16)(g[j][e] + rbq[e]);
          hv[e] = (v > (f16)0.0f) ? v : (f16)0.0f;
        }
        *(f16x8_t*)&h1[row * H1S2 + q5 * 8] = hv;
      }
    }
    __syncthreads();

    // next-tile metadata during first phase of each tile
    if (t == 0 && kh == 0 && more && tid < 128) {
      int pos = s0 + (ti + 1) * 128 + tid;
      if (pos < s1) {
        sends2[nb][tid] = ssend[pos];
        float2 rr = srel[pos];
        relv2[nb][tid][0] = rr.x;
        relv2[nb][tid][1] = rr.y;
      } else {
        sends2[nb][tid] = 0; relv2[nb][tid][0] = 0.f; relv2[nb][tid][1] = 0.f;
      }
    }

    if (kh == 0) {
      #pragma unroll
      for (int rt = 0; rt < 4; rt++)
        #pragma unroll
        for (int r = 0; r < 16; r++) acc[rt][r] = 0.f;
    }

    f16x8_t bb[2];
    bb[0] = Bp[(size_t)(((t * 32 + kh * 16 + 0) * 8 + w) * 64 + lane)];
    bb[1] = Bp[(size_t)(((t * 32 + kh * 16 + 1) * 8 + w) * 64 + lane)];

    // prefetch next phase's gather (issued after initial B loads; FIFO keeps
    // it in flight across the kc loop)
    if (kh == 0) {
      #pragma unroll
      for (int j = 0; j < 8; j++)
        g[j] = SAc[(size_t)(t * 512 + sends2[cb][rb0 + 16 * j]) * 64 + 32 + q5];
    } else if (t == 0) {
      #pragma unroll
      for (int j = 0; j < 8; j++)
        g[j] = SAc[(size_t)(512 + sends2[cb][rb0 + 16 * j]) * 64 + q5];
    } else if (more) {
      #pragma unroll
      for (int j = 0; j < 8; j++)
        g[j] = SAc[(size_t)sends2[nb][rb0 + 16 * j] * 64 + q5];
    }

    for (int kc = 0; kc < 16; kc++) {
      int pb = kc & 1;
      #pragma unroll
      for (int rt = 0; rt < 4; rt++) {
        f16x8_t af = *(const f16x8_t*)&h1[(rt * 32 + l31) * H1S2 + kc * 16 + hlf * 8];
        acc[rt] = __builtin_amdgcn_mfma_f32_32x32x16_f16(af, bb[pb], acc[rt], 0, 0, 0);
      }
      if (kc + 2 < 16)
        bb[pb] = Bp[(size_t)(((t * 32 + kh * 16 + kc + 2) * 8 + w) * 64 + lane)];
    }

    // ---- epilogue after the second K-half ----
    if (kh == 1) {
      int col = w * 32 + l31;
      float b2c = b2s[t][col];
      float csum = 0.0f;
      #pragma unroll
      for (int rt = 0; rt < 4; rt++)
        #pragma unroll
        for (int r = 0; r < 16; r++) {
          int row = rt * 32 + (r & 3) + 8 * (r >> 2) + 4 * hlf;
          float v = fmaxf(acc[rt][r] + b2c, 0.0f);
          csum += v * relv2[cb][row][t];
        }
      csum += __shfl_xor(csum, 32, 64);
      if (hlf == 0) aggL[col] += csum;   // waves own disjoint cols
    }
    __syncthreads();
  }

  if (tid < 256) agg[(size_t)c * 256 + tid] = aggL[tid];
}

// ---------------- output MLP: three MFMA layer kernels ----------------
__global__ __launch_bounds__(256) void k_omlp1(const float* __restrict__ agg,
    const f16* __restrict__ Wo1p, const float* __restrict__ bo1, f16* __restrict__ h1o)
{
  int tid = threadIdx.x, lane = tid & 63, w = tid >> 6;
  int hlf = lane >> 5, l31 = lane & 31;
  int br = blockIdx.x, bc = blockIdx.y;
  f32x16_t acc[2][2];
  #pragma unroll
  for (int rt = 0; rt < 2; rt++)
    #pragma unroll
    for (int ctl = 0; ctl < 2; ctl++)
      #pragma unroll
      for (int r = 0; r < 16; r++) acc[rt][ctl][r] = 0.f;
  for (int kc = 0; kc < 16; kc++) {
    f16x8_t af[2];
    #pragma unroll
    for (int rt = 0; rt < 2; rt++) {
      const float4* p = (const float4*)&agg[(size_t)(br * 64 + rt * 32 + l31) * 256 + kc * 16 + hlf * 8];
      float4 u0 = p[0], u1 = p[1];
      af[rt] = (f16x8_t){(f16)u0.x, (f16)u0.y, (f16)u0.z, (f16)u0.w,
                         (f16)u1.x, (f16)u1.y, (f16)u1.z, (f16)u1.w};
    }
    #pragma unroll
    for (int ctl = 0; ctl < 2; ctl++) {
      f16x8_t bfr = *(const f16x8_t*)&Wo1p[((size_t)(kc * 16 + bc * 8 + 2 * w + ctl) * 64 + lane) * 8];
      #pragma unroll
      for (int rt = 0; rt < 2; rt++)
        acc[rt][ctl] = __builtin_amdgcn_mfma_f32_32x32x16_f16(af[rt], bfr, acc[rt][ctl], 0, 0, 0);
    }
  }
  #pragma unroll
  for (int ctl = 0; ctl < 2; ctl++) {
    int col = bc * 256 + (2 * w + ctl) * 32 + l31;
    float bias = bo1[col];
    #pragma unroll
    for (int rt = 0; rt < 2; rt++)
      #pragma unroll
      for (int r = 0; r < 16; r++) {
        int row = br * 64 + rt * 32 + (r & 3) + 8 * (r >> 2) + 4 * hlf;
        h1o[(size_t)row * 512 + col] = (f16)fmaxf(acc[rt][ctl][r] + bias, 0.f);
      }
  }
}

__global__ __launch_bounds__(256) void k_omlp2(const f16* __restrict__ h1o,
    const f16* __restrict__ Wo2p, const float* __restrict__ bo2, f16* __restrict__ h2o)
{
  int tid = threadIdx.x, lane = tid & 63, w = tid >> 6;
  int hlf = lane >> 5, l31 = lane & 31;
  int br = blockIdx.x, bc = blockIdx.y;
  f32x16_t acc[2][2];
  #pragma unroll
  for (int rt = 0; rt < 2; rt++)
    #pragma unroll
    for (int ctl = 0; ctl < 2; ctl++)
      #pragma unroll
      for (int r = 0; r < 16; r++) acc[rt][ctl][r] = 0.f;
  for (int kc = 0; kc < 32; kc++) {
    f16x8_t af[2];
    #pragma unroll
    for (int rt = 0; rt < 2; rt++)
      af[rt] = *(const f16x8_t*)&h1o[(size_t)(br * 64 + rt * 32 + l31) * 512 + kc * 16 + hlf * 8];
    #pragma unroll
    for (int ctl = 0; ctl < 2; ctl++) {
      f16x8_t bfr = *(const f16x8_t*)&Wo2p[((size_t)(kc * 16 + bc * 8 + 2 * w + ctl) * 64 + lane) * 8];
      #pragma unroll
      for (int rt = 0; rt < 2; rt++)
        acc[rt][ctl] = __builtin_amdgcn_mfma_f32_32x32x16_f16(af[rt], bfr, acc[rt][ctl], 0, 0, 0);
    }
  }
  #pragma unroll
  for (int ctl = 0; ctl < 2; ctl++) {
    int col = bc * 256 + (2 * w + ctl) * 32 + l31;
    float bias = bo2[col];
    #pragma unroll
    for (int rt = 0; rt < 2; rt++)
      #pragma unroll
      for (int r = 0; r < 16; r++) {
        int row = br * 64 + rt * 32 + (r & 3) + 8 * (r >> 2) + 4 * hlf;
        h2o[(size_t)row * 512 + col] = (f16)fmaxf(acc[rt][ctl][r] + bias, 0.f);
      }
  }
}

__global__ __launch_bounds__(256) void k_omlp3(const f16* __restrict__ h2o,
    const f16* __restrict__ Wo3p, const float* __restrict__ bo3, float* __restrict__ out)
{
  int tid = threadIdx.x, lane = tid & 63, w = tid >> 6;
  int hlf = lane >> 5, l31 = lane & 31;
  int br = blockIdx.x;
  f32x16_t acc[2][2];
  #pragma unroll
  for (int rt = 0; rt < 2; rt++)
    #pragma unroll
    for (int ctl = 0; ctl < 2; ctl++)
      #pragma unroll
      for (int r = 0; r < 16; r++) acc[rt][ctl][r] = 0.f;
  for (int kc = 0; kc < 32; kc++) {
    f16x8_t af[2];
    #pragma unroll
    for (int rt = 0; rt < 2; rt++)
      af[rt] = *(const f16x8_t*)&h2o[(size_t)(br * 64 + rt * 32 + l31) * 512 + kc * 16 + hlf * 8];
    #pragma unroll
    for (int ctl = 0; ctl < 2; ctl++) {
      f16x8_t bfr = *(const f16x8_t*)&Wo3p[((size_t)(kc * 8 + 2 * w + ctl) * 64 + lane) * 8];
      #pragma unroll
      for (int rt = 0; rt < 2; rt++)
        acc[rt][ctl] = __builtin_amdgcn_mfma_f32_32x32x16_f16(af[rt], bfr, acc[rt][ctl], 0, 0, 0);
    }
  }
  #pragma unroll
  for (int ctl = 0; ctl < 2; ctl++) {
    int col = (2 * w + ctl) * 32 + l31;
    float bias = bo3[col];
    #pragma unroll
    for (int rt = 0; rt < 2; rt++)
      #pragma unroll
      for (int r = 0; r < 16; r++) {
        int row = br * 64 + rt * 32 + (r & 3) + 8 * (r >> 2) + 4 * hlf;
        out[(size_t)row * 256 + col] = acc[rt][ctl][r] + bias;
      }
  }
}

// ---------------- launcher ----------------
extern "C" void kernel_launch(void* const* d_in, const int* in_sizes, int n_in,
                              void* d_out, int out_size, void* d_ws, size_t ws_size,
                              hipStream_t stream)
{
  (void)in_sizes; (void)n_in; (void)out_size; (void)ws_size;
  const float* inputs = (const float*)d_in[0];
  const float* rel    = (const float*)d_in[1];
  const float* W1     = (const float*)d_in[2];
  const float* b1     = (const float*)d_in[3];
  const float* W2     = (const float*)d_in[4];
  const float* b2     = (const float*)d_in[5];
  const float* Wo1    = (const float*)d_in[6];
  const float* bo1    = (const float*)d_in[7];
  const float* Wo2    = (const float*)d_in[8];
  const float* bo2    = (const float*)d_in[9];
  const float* Wo3    = (const float*)d_in[10];
  const float* bo3    = (const float*)d_in[11];
  const int* send_idx = (const int*)d_in[12];
  const int* rec_idx  = (const int*)d_in[13];
  float* out = (float*)d_out;

  char* ws = (char*)d_ws;
  f16*    SA        = (f16*)   (ws);                              // 1 MB
  f16*    RB        = (f16*)   (ws + (1u << 20));                 // 1 MB
  f16*    W2p       = (f16*)   (ws + (2u << 20));                 // 512 KB
  float*  agg       = (float*) (ws + (2560u << 10));              // 512 KB
  int*    hist_part = (int*)   (ws + (3u << 20));                 // 128 KB
  int*    seg       = (int*)   (ws + (3u << 20) + (128u << 10));  // 4 KB
  int*    base      = (int*)   (ws + (3u << 20) + (132u << 10));  // 128 KB
  int*    ssend     = (int*)   (ws + (3584u << 10));              // 1 MB
  float2* srel      = (float2*)(ws + (4608u << 10));              // 2 MB
  f16*    Wo1p      = (f16*)   (ws + (6656u << 10));              // 256 KB
  f16*    Wo2p      = (f16*)   (ws + (6912u << 10));              // 512 KB
  f16*    Wo3p      = (f16*)   (ws + (7424u << 10));              // 256 KB
  f16*    h1o       = (f16*)   (ws + (7680u << 10));              // 512 KB
  f16*    h2o       = (f16*)   (ws + (8192u << 10));              // 512 KB (total 8.5 MB)

  k_prep    <<<dim3(704), dim3(256),  0, stream>>>(inputs, W1, b1, W2, rec_idx,
                                                   Wo1, Wo2, Wo3,
                                                   SA, RB, W2p, Wo1p, Wo2p, Wo3p, hist_part);
  k_scan    <<<dim3(1),   dim3(512),  0, stream>>>(hist_part, seg, base);
  k_scatter3<<<dim3(64),  dim3(1024), 0, stream>>>(rec_idx, send_idx, rel, base, ssend, srel);
  k_edges   <<<dim3(512), dim3(512),  0, stream>>>(SA, RB, W2p, b2, ssend, srel, seg, agg);
  k_omlp1   <<<dim3(8,2), dim3(256),  0, stream>>>(agg, Wo1p, bo1, h1o);
  k_omlp2   <<<dim3(8,2), dim3(256),  0, stream>>>(h1o, Wo2p, bo2, h2o);
  k_omlp3   <<<dim3(8),   dim3(256),  0, stream>>>(h2o, Wo3p, bo3, out);
}

// Round 10
// 310.873 us; speedup vs baseline: 1.1150x; 1.0681x over previous
//
#include <hip/hip_runtime.h>

#define C_N   512
#define E_N   261632

typedef _Float16 f16;
typedef _Float16 f16x8_t __attribute__((ext_vector_type(8)));
typedef float    f32x16_t __attribute__((ext_vector_type(16)));

// ---------------- fused prep (all pack + hist) ----------------
// [0,256): W1 pack (4 mats: t x {SA,RB}, K=256, N=512)
// [256,384): W2 pack  [384,448): hist  [448,512): Wo1 pack
// [512,640): Wo2 pack [640,704): Wo3 pack
__global__ __launch_bounds__(256) void k_prep(
    const float* __restrict__ W1, const float* __restrict__ W2,
    const int* __restrict__ rec,
    const float* __restrict__ Wo1, const float* __restrict__ Wo2, const float* __restrict__ Wo3,
    f16* __restrict__ W1p, f16* __restrict__ W2p,
    f16* __restrict__ Wo1p, f16* __restrict__ Wo2p, f16* __restrict__ Wo3p,
    int* __restrict__ hist_part)
{
  int bid = blockIdx.x;
  if (bid < 256) {
    // W1p[mi][((kc*16+nt)*64+lane)*8+j]; mi = t*2+half
    int gid  = bid * 256 + threadIdx.x;           // 0..65535
    int lane = gid & 63;
    int nt   = (gid >> 6) & 15;
    int kc   = (gid >> 10) & 15;
    int mi   = gid >> 14;                          // 0..3
    int t    = mi >> 1, half = mi & 1;
    const float* src = W1 + (size_t)t * 512 * 512 + (size_t)half * 256 * 512;
    int n  = nt * 32 + (lane & 31);
    int k0 = kc * 16 + (lane >> 5) * 8;
    f16x8_t v;
    #pragma unroll
    for (int j = 0; j < 8; j++) v[j] = (f16)src[(size_t)(k0 + j) * 512 + n];
    *(f16x8_t*)(W1p + (size_t)gid * 8) = v;
  } else if (bid < 384) {
    int gid  = (bid - 256) * 256 + threadIdx.x;   // 0..32767
    int lane = gid & 63;
    int ct   = (gid >> 6) & 7;
    int kc   = (gid >> 9) & 31;
    int t    = gid >> 14;
    int n    = ct * 32 + (lane & 31);
    int k0   = kc * 16 + (lane >> 5) * 8;
    const float* src = W2 + (size_t)t * 512 * 256;
    f16x8_t v;
    #pragma unroll
    for (int j = 0; j < 8; j++) v[j] = (f16)src[(size_t)(k0 + j) * 256 + n];
    *(f16x8_t*)(W2p + (size_t)gid * 8) = v;
  } else if (bid < 448) {
    int hb = bid - 384;
    __shared__ int lh[512];
    for (int i = threadIdx.x; i < 512; i += 256) lh[i] = 0;
    __syncthreads();
    int e0 = hb * (E_N / 64);
    for (int i = threadIdx.x; i < E_N / 64; i += 256)
      atomicAdd(&lh[rec[e0 + i]], 1);
    __syncthreads();
    for (int i = threadIdx.x; i < 512; i += 256)
      hist_part[hb * 512 + i] = lh[i];
  } else if (bid < 512) {
    int gid  = (bid - 448) * 256 + threadIdx.x;   // 0..16383
    int lane = gid & 63;
    int ct   = (gid >> 6) & 15;
    int kc   = gid >> 10;                          // 0..15
    int n    = ct * 32 + (lane & 31);
    int k0   = kc * 16 + (lane >> 5) * 8;
    f16x8_t v;
    #pragma unroll
    for (int j = 0; j < 8; j++) v[j] = (f16)Wo1[(size_t)(k0 + j) * 512 + n];
    *(f16x8_t*)(Wo1p + (size_t)gid * 8) = v;
  } else if (bid < 640) {
    int gid  = (bid - 512) * 256 + threadIdx.x;   // 0..32767
    int lane = gid & 63;
    int ct   = (gid >> 6) & 15;
    int kc   = gid >> 10;                          // 0..31
    int n    = ct * 32 + (lane & 31);
    int k0   = kc * 16 + (lane >> 5) * 8;
    f16x8_t v;
    #pragma unroll
    for (int j = 0; j < 8; j++) v[j] = (f16)Wo2[(size_t)(k0 + j) * 512 + n];
    *(f16x8_t*)(Wo2p + (size_t)gid * 8) = v;
  } else {
    int gid  = (bid - 640) * 256 + threadIdx.x;   // 0..16383
    int lane = gid & 63;
    int ct   = (gid >> 6) & 7;
    int kc   = gid >> 9;                           // 0..31
    int n    = ct * 32 + (lane & 31);
    int k0   = kc * 16 + (lane >> 5) * 8;
    f16x8_t v;
    #pragma unroll
    for (int j = 0; j < 8; j++) v[j] = (f16)Wo3[(size_t)(k0 + j) * 256 + n];
    *(f16x8_t*)(Wo3p + (size_t)gid * 8) = v;
  }
}

// ---------------- SA/RB via MFMA: inputs[512,256] @ W1half[256,512] ----------------
// grid (8 M-tiles, 2 N-halves, 4 mats); RB gets +b1
__global__ __launch_bounds__(256) void k_sarb(const float* __restrict__ inputs,
    const f16* __restrict__ W1p, const float* __restrict__ b1,
    f16* __restrict__ SA, f16* __restrict__ RB)
{
  int tid = threadIdx.x, lane = tid & 63, w = tid >> 6;
  int hlf = lane >> 5, l31 = lane & 31;
  int br = blockIdx.x, bc = blockIdx.y, mi = blockIdx.z;
  int t = mi >> 1, half = mi & 1;
  const f16* Bmat = W1p + (size_t)mi * (256 * 512);
  f32x16_t acc[2][2];
  #pragma unroll
  for (int rt = 0; rt < 2; rt++)
    #pragma unroll
    for (int ctl = 0; ctl < 2; ctl++)
      #pragma unroll
      for (int r = 0; r < 16; r++) acc[rt][ctl][r] = 0.f;
  for (int kc = 0; kc < 16; kc++) {
    f16x8_t af[2];
    #pragma unroll
    for (int rt = 0; rt < 2; rt++) {
      const float4* p = (const float4*)&inputs[(size_t)(br * 64 + rt * 32 + l31) * 256 + kc * 16 + hlf * 8];
      float4 u0 = p[0], u1 = p[1];
      af[rt] = (f16x8_t){(f16)u0.x, (f16)u0.y, (f16)u0.z, (f16)u0.w,
                         (f16)u1.x, (f16)u1.y, (f16)u1.z, (f16)u1.w};
    }
    #pragma unroll
    for (int ctl = 0; ctl < 2; ctl++) {
      f16x8_t bfr = *(const f16x8_t*)&Bmat[((size_t)(kc * 16 + bc * 8 + 2 * w + ctl) * 64 + lane) * 8];
      #pragma unroll
      for (int rt = 0; rt < 2; rt++)
        acc[rt][ctl] = __builtin_amdgcn_mfma_f32_32x32x16_f16(af[rt], bfr, acc[rt][ctl], 0, 0, 0);
    }
  }
  f16* dst = (half == 0) ? SA : RB;
  #pragma unroll
  for (int ctl = 0; ctl < 2; ctl++) {
    int col = bc * 256 + (2 * w + ctl) * 32 + l31;
    float bias = (half == 1) ? b1[t * 512 + col] : 0.f;
    #pragma unroll
    for (int rt = 0; rt < 2; rt++)
      #pragma unroll
      for (int r = 0; r < 16; r++) {
        int row = br * 64 + rt * 32 + (r & 3) + 8 * (r >> 2) + 4 * hlf;
        dst[((size_t)(t * 512 + row)) * 512 + col] = (f16)(acc[rt][ctl][r] + bias);
      }
  }
}

// ---------------- scan ----------------
__global__ void k_scan(const int* __restrict__ hist_part, int* __restrict__ seg,
                       int* __restrict__ base)
{
  __shared__ int s[512];
  int tid = threadIdx.x;
  int tot = 0;
  #pragma unroll 8
  for (int b = 0; b < 64; b++) tot += hist_part[b * 512 + tid];
  s[tid] = tot;
  __syncthreads();
  for (int off = 1; off < 512; off <<= 1) {
    int v = (tid >= off) ? s[tid - off] : 0;
    __syncthreads();
    s[tid] += v;
    __syncthreads();
  }
  int excl = s[tid] - tot;
  seg[tid] = excl;
  if (tid == 0) seg[512] = E_N;
  int run = excl;
  for (int b = 0; b < 64; b++) {
    base[b * 512 + tid] = run;
    run += hist_part[b * 512 + tid];
  }
}

// ---------------- scatter ----------------
__global__ __launch_bounds__(1024) void k_scatter3(const int* __restrict__ rec,
    const int* __restrict__ send, const float* __restrict__ rel,
    const int* __restrict__ base, int* __restrict__ ssend, float2* __restrict__ srel)
{
  __shared__ int lh[512];
  __shared__ int lb[512];
  int b = blockIdx.x;
  int e0 = b * (E_N / 64);
  for (int i = threadIdx.x; i < 512; i += 1024) { lh[i] = 0; lb[i] = base[b * 512 + i]; }
  __syncthreads();
  for (int i = threadIdx.x; i < E_N / 64; i += 1024) {
    int e = e0 + i;
    int r = rec[e];
    int p = lb[r] + atomicAdd(&lh[r], 1);
    ssend[p] = send[e];
    srel[p]  = make_float2(rel[2 * (size_t)e], rel[2 * (size_t)e + 1]);
  }
}

// ---------------- K5: edge MLP + aggregation (unchanged from R9) ----------------
#define H1S2 264

__global__ __launch_bounds__(512, 4) void k_edges(
    const f16* __restrict__ SA, const f16* __restrict__ RB,
    const f16* __restrict__ W2p, const float* __restrict__ b2,
    const int* __restrict__ ssend, const float2* __restrict__ srel,
    const int* __restrict__ seg, float* __restrict__ agg)
{
  __shared__ f16   h1[128 * H1S2];
  __shared__ f16   rbs[2][512];
  __shared__ float b2s[2][256];
  __shared__ float aggL[256];
  __shared__ float relv2[2][128][2];
  __shared__ int   sends2[2][128];

  int c    = blockIdx.x;
  int tid  = threadIdx.x;
  int lane = tid & 63;
  int w    = tid >> 6;
  int hlf  = lane >> 5;
  int l31  = lane & 31;
  int q5   = tid & 31;
  int rb0  = tid >> 5;

  if (tid < 128) {
    int t = tid >> 6, qq = tid & 63;
    *(f16x8_t*)&rbs[t][qq * 8] = *(const f16x8_t*)&RB[((size_t)(t * 512 + c)) * 512 + qq * 8];
  }
  if (tid < 256) aggL[tid] = 0.0f;
  { int t = (tid >> 8) & 1, col = tid & 255; b2s[t][col] = b2[t * 256 + col]; }

  int s0 = seg[c], s1 = seg[c + 1];
  int nt = (s1 - s0 + 127) >> 7;

  if (nt > 0 && tid < 128) {
    int pos = s0 + tid;
    if (pos < s1) {
      sends2[0][tid] = ssend[pos];
      float2 rr = srel[pos];
      relv2[0][tid][0] = rr.x;
      relv2[0][tid][1] = rr.y;
    } else {
      sends2[0][tid] = 0; relv2[0][tid][0] = 0.f; relv2[0][tid][1] = 0.f;
    }
  }
  __syncthreads();

  f16x8_t g[8];
  const f16x8_t* SAc = (const f16x8_t*)SA;
  const f16x8_t* Bp  = (const f16x8_t*)W2p;
  f32x16_t acc[4];

  if (nt > 0) {
    #pragma unroll
    for (int j = 0; j < 8; j++)
      g[j] = SAc[(size_t)sends2[0][rb0 + 16 * j] * 64 + q5];
  }

  for (int ph = 0; ph < 4 * nt; ph++) {
    int ti  = ph >> 2;
    int t   = (ph >> 1) & 1;
    int kh  = ph & 1;
    int cb  = ti & 1;
    int nb  = cb ^ 1;
    bool more = (ti + 1 < nt);

    {
      f16x8_t rbq = *(const f16x8_t*)&rbs[t][(kh * 32 + q5) * 8];
      #pragma unroll
      for (int j = 0; j < 8; j++) {
        int row = rb0 + 16 * j;
        f16x8_t hv;
        #pragma unroll
        for (int e = 0; e < 8; e++) {
          f16 v = (f16)(g[j][e] + rbq[e]);
          hv[e] = (v > (f16)0.0f) ? v : (f16)0.0f;
        }
        *(f16x8_t*)&h1[row * H1S2 + q5 * 8] = hv;
      }
    }
    __syncthreads();

    if (t == 0 && kh == 0 && more && tid < 128) {
      int pos = s0 + (ti + 1) * 128 + tid;
      if (pos < s1) {
        sends2[nb][tid] = ssend[pos];
        float2 rr = srel[pos];
        relv2[nb][tid][0] = rr.x;
        relv2[nb][tid][1] = rr.y;
      } else {
        sends2[nb][tid] = 0; relv2[nb][tid][0] = 0.f; relv2[nb][tid][1] = 0.f;
      }
    }

    if (kh == 0) {
      #pragma unroll
      for (int rt = 0; rt < 4; rt++)
        #pragma unroll
        for (int r = 0; r < 16; r++) acc[rt][r] = 0.f;
    }

    f16x8_t bb[2];
    bb[0] = Bp[(size_t)(((t * 32 + kh * 16 + 0) * 8 + w) * 64 + lane)];
    bb[1] = Bp[(size_t)(((t * 32 + kh * 16 + 1) * 8 + w) * 64 + lane)];

    if (kh == 0) {
      #pragma unroll
      for (int j = 0; j < 8; j++)
        g[j] = SAc[(size_t)(t * 512 + sends2[cb][rb0 + 16 * j]) * 64 + 32 + q5];
    } else if (t == 0) {
      #pragma unroll
      for (int j = 0; j < 8; j++)
        g[j] = SAc[(size_t)(512 + sends2[cb][rb0 + 16 * j]) * 64 + q5];
    } else if (more) {
      #pragma unroll
      for (int j = 0; j < 8; j++)
        g[j] = SAc[(size_t)sends2[nb][rb0 + 16 * j] * 64 + q5];
    }

    for (int kc = 0; kc < 16; kc++) {
      int pb = kc & 1;
      #pragma unroll
      for (int rt = 0; rt < 4; rt++) {
        f16x8_t af = *(const f16x8_t*)&h1[(rt * 32 + l31) * H1S2 + kc * 16 + hlf * 8];
        acc[rt] = __builtin_amdgcn_mfma_f32_32x32x16_f16(af, bb[pb], acc[rt], 0, 0, 0);
      }
      if (kc + 2 < 16)
        bb[pb] = Bp[(size_t)(((t * 32 + kh * 16 + kc + 2) * 8 + w) * 64 + lane)];
    }

    if (kh == 1) {
      int col = w * 32 + l31;
      float b2c = b2s[t][col];
      float csum = 0.0f;
      #pragma unroll
      for (int rt = 0; rt < 4; rt++)
        #pragma unroll
        for (int r = 0; r < 16; r++) {
          int row = rt * 32 + (r & 3) + 8 * (r >> 2) + 4 * hlf;
          float v = fmaxf(acc[rt][r] + b2c, 0.0f);
          csum += v * relv2[cb][row][t];
        }
      csum += __shfl_xor(csum, 32, 64);
      if (hlf == 0) aggL[col] += csum;
    }
    __syncthreads();
  }

  if (tid < 256) agg[(size_t)c * 256 + tid] = aggL[tid];
}

// ---------------- output MLP ----------------
__global__ __launch_bounds__(256) void k_omlp1(const float* __restrict__ agg,
    const f16* __restrict__ Wo1p, const float* __restrict__ bo1, f16* __restrict__ h1o)
{
  int tid = threadIdx.x, lane = tid & 63, w = tid >> 6;
  int hlf = lane >> 5, l31 = lane & 31;
  int br = blockIdx.x, bc = blockIdx.y;
  f32x16_t acc[2][2];
  #pragma unroll
  for (int rt = 0; rt < 2; rt++)
    #pragma unroll
    for (int ctl = 0; ctl < 2; ctl++)
      #pragma unroll
      for (int r = 0; r < 16; r++) acc[rt][ctl][r] = 0.f;
  for (int kc = 0; kc < 16; kc++) {
    f16x8_t af[2];
    #pragma unroll
    for (int rt = 0; rt < 2; rt++) {
      const float4* p = (const float4*)&agg[(size_t)(br * 64 + rt * 32 + l31) * 256 + kc * 16 + hlf * 8];
      float4 u0 = p[0], u1 = p[1];
      af[rt] = (f16x8_t){(f16)u0.x, (f16)u0.y, (f16)u0.z, (f16)u0.w,
                         (f16)u1.x, (f16)u1.y, (f16)u1.z, (f16)u1.w};
    }
    #pragma unroll
    for (int ctl = 0; ctl < 2; ctl++) {
      f16x8_t bfr = *(const f16x8_t*)&Wo1p[((size_t)(kc * 16 + bc * 8 + 2 * w + ctl) * 64 + lane) * 8];
      #pragma unroll
      for (int rt = 0; rt < 2; rt++)
        acc[rt][ctl] = __builtin_amdgcn_mfma_f32_32x32x16_f16(af[rt], bfr, acc[rt][ctl], 0, 0, 0);
    }
  }
  #pragma unroll
  for (int ctl = 0; ctl < 2; ctl++) {
    int col = bc * 256 + (2 * w + ctl) * 32 + l31;
    float bias = bo1[col];
    #pragma unroll
    for (int rt = 0; rt < 2; rt++)
      #pragma unroll
      for (int r = 0; r < 16; r++) {
        int row = br * 64 + rt * 32 + (r & 3) + 8 * (r >> 2) + 4 * hlf;
        h1o[(size_t)row * 512 + col] = (f16)fmaxf(acc[rt][ctl][r] + bias, 0.f);
      }
  }
}

__global__ __launch_bounds__(256) void k_omlp2(const f16* __restrict__ h1o,
    const f16* __restrict__ Wo2p, const float* __restrict__ bo2, f16* __restrict__ h2o)
{
  int tid = threadIdx.x, lane = tid & 63, w = tid >> 6;
  int hlf = lane >> 5, l31 = lane & 31;
  int br = blockIdx.x, bc = blockIdx.y;
  f32x16_t acc[2][2];
  #pragma unroll
  for (int rt = 0; rt < 2; rt++)
    #pragma unroll
    for (int ctl = 0; ctl < 2; ctl++)
      #pragma unroll
      for (int r = 0; r < 16; r++) acc[rt][ctl][r] = 0.f;
  for (int kc = 0; kc < 32; kc++) {
    f16x8_t af[2];
    #pragma unroll
    for (int rt = 0; rt < 2; rt++)
      af[rt] = *(const f16x8_t*)&h1o[(size_t)(br * 64 + rt * 32 + l31) * 512 + kc * 16 + hlf * 8];
    #pragma unroll
    for (int ctl = 0; ctl < 2; ctl++) {
      f16x8_t bfr = *(const f16x8_t*)&Wo2p[((size_t)(kc * 16 + bc * 8 + 2 * w + ctl) * 64 + lane) * 8];
      #pragma unroll
      for (int rt = 0; rt < 2; rt++)
        acc[rt][ctl] = __builtin_amdgcn_mfma_f32_32x32x16_f16(af[rt], bfr, acc[rt][ctl], 0, 0, 0);
    }
  }
  #pragma unroll
  for (int ctl = 0; ctl < 2; ctl++) {
    int col = bc * 256 + (2 * w + ctl) * 32 + l31;
    float bias = bo2[col];
    #pragma unroll
    for (int rt = 0; rt < 2; rt++)
      #pragma unroll
      for (int r = 0; r < 16; r++) {
        int row = br * 64 + rt * 32 + (r & 3) + 8 * (r >> 2) + 4 * hlf;
        h2o[(size_t)row * 512 + col] = (f16)fmaxf(acc[rt][ctl][r] + bias, 0.f);
      }
  }
}

__global__ __launch_bounds__(256) void k_omlp3(const f16* __restrict__ h2o,
    const f16* __restrict__ Wo3p, const float* __restrict__ bo3, float* __restrict__ out)
{
  int tid = threadIdx.x, lane = tid & 63, w = tid >> 6;
  int hlf = lane >> 5, l31 = lane & 31;
  int br = blockIdx.x;
  f32x16_t acc[2][2];
  #pragma unroll
  for (int rt = 0; rt < 2; rt++)
    #pragma unroll
    for (int ctl = 0; ctl < 2; ctl++)
      #pragma unroll
      for (int r = 0; r < 16; r++) acc[rt][ctl][r] = 0.f;
  for (int kc = 0; kc < 32; kc++) {
    f16x8_t af[2];
    #pragma unroll
    for (int rt = 0; rt < 2; rt++)
      af[rt] = *(const f16x8_t*)&h2o[(size_t)(br * 64 + rt * 32 + l31) * 512 + kc * 16 + hlf * 8];
    #pragma unroll
    for (int ctl = 0; ctl < 2; ctl++) {
      f16x8_t bfr = *(const f16x8_t*)&Wo3p[((size_t)(kc * 8 + 2 * w + ctl) * 64 + lane) * 8];
      #pragma unroll
      for (int rt = 0; rt < 2; rt++)
        acc[rt][ctl] = __builtin_amdgcn_mfma_f32_32x32x16_f16(af[rt], bfr, acc[rt][ctl], 0, 0, 0);
    }
  }
  #pragma unroll
  for (int ctl = 0; ctl < 2; ctl++) {
    int col = (2 * w + ctl) * 32 + l31;
    float bias = bo3[col];
    #pragma unroll
    for (int rt = 0; rt < 2; rt++)
      #pragma unroll
      for (int r = 0; r < 16; r++) {
        int row = br * 64 + rt * 32 + (r & 3) + 8 * (r >> 2) + 4 * hlf;
        out[(size_t)row * 256 + col] = acc[rt][ctl][r] + bias;
      }
  }
}

// ---------------- launcher ----------------
extern "C" void kernel_launch(void* const* d_in, const int* in_sizes, int n_in,
                              void* d_out, int out_size, void* d_ws, size_t ws_size,
                              hipStream_t stream)
{
  (void)in_sizes; (void)n_in; (void)out_size; (void)ws_size;
  const float* inputs = (const float*)d_in[0];
  const float* rel    = (const float*)d_in[1];
  const float* W1     = (const float*)d_in[2];
  const float* b1     = (const float*)d_in[3];
  const float* W2     = (const float*)d_in[4];
  const float* b2     = (const float*)d_in[5];
  const float* Wo1    = (const float*)d_in[6];
  const float* bo1    = (const float*)d_in[7];
  const float* Wo2    = (const float*)d_in[8];
  const float* bo2    = (const float*)d_in[9];
  const float* Wo3    = (const float*)d_in[10];
  const float* bo3    = (const float*)d_in[11];
  const int* send_idx = (const int*)d_in[12];
  const int* rec_idx  = (const int*)d_in[13];
  float* out = (float*)d_out;

  char* ws = (char*)d_ws;
  f16*    SA        = (f16*)   (ws);                              // 1 MB
  f16*    RB        = (f16*)   (ws + (1u << 20));                 // 1 MB
  f16*    W2p       = (f16*)   (ws + (2u << 20));                 // 512 KB
  float*  agg       = (float*) (ws + (2560u << 10));              // 512 KB
  int*    hist_part = (int*)   (ws + (3u << 20));                 // 128 KB
  int*    seg       = (int*)   (ws + (3u << 20) + (128u << 10));  // 4 KB
  int*    base      = (int*)   (ws + (3u << 20) + (132u << 10));  // 128 KB
  int*    ssend     = (int*)   (ws + (3584u << 10));              // 1 MB
  float2* srel      = (float2*)(ws + (4608u << 10));              // 2 MB
  f16*    Wo1p      = (f16*)   (ws + (6656u << 10));              // 256 KB
  f16*    Wo2p      = (f16*)   (ws + (6912u << 10));              // 512 KB
  f16*    Wo3p      = (f16*)   (ws + (7424u << 10));              // 256 KB
  f16*    h1o       = (f16*)   (ws + (7680u << 10));              // 512 KB
  f16*    h2o       = (f16*)   (ws + (8192u << 10));              // 512 KB
  f16*    W1p       = (f16*)   (ws + (8704u << 10));              // 1 MB (total 9.5 MB)

  k_prep    <<<dim3(704),     dim3(256),  0, stream>>>(W1, W2, rec_idx, Wo1, Wo2, Wo3,
                                                       W1p, W2p, Wo1p, Wo2p, Wo3p, hist_part);
  k_sarb    <<<dim3(8, 2, 4), dim3(256),  0, stream>>>(inputs, W1p, b1, SA, RB);
  k_scan    <<<dim3(1),       dim3(512),  0, stream>>>(hist_part, seg, base);
  k_scatter3<<<dim3(64),      dim3(1024), 0, stream>>>(rec_idx, send_idx, rel, base, ssend, srel);
  k_edges   <<<dim3(512),     dim3(512),  0, stream>>>(SA, RB, W2p, b2, ssend, srel, seg, agg);
  k_omlp1   <<<dim3(8, 2),    dim3(256),  0, stream>>>(agg, Wo1p, bo1, h1o);
  k_omlp2   <<<dim3(8, 2),    dim3(256),  0, stream>>>(h1o, Wo2p, bo2, h2o);
  k_omlp3   <<<dim3(8),       dim3(256),  0, stream>>>(h2o, Wo3p, bo3, out);
}

// Round 11
// 306.314 us; speedup vs baseline: 1.1316x; 1.0149x over previous
//
#include <hip/hip_runtime.h>

#define C_N   512
#define E_N   261632
#define CAP   768          // bucket capacity per receiver (max count ~590)

typedef _Float16 f16;
typedef _Float16 f16x8_t __attribute__((ext_vector_type(8)));
typedef float    f32x16_t __attribute__((ext_vector_type(16)));

// ---------------- K1: everything-prep ----------------
// [0,64):   SA/RB MFMA GEMM (reads raw W1 as B-frags)
// [64,192): W2 pack   [192,256): Wo1 pack   [256,384): Wo2 pack
// [384,448): Wo3 pack [448]: zero scatter cursors
__global__ __launch_bounds__(256) void k_prep_all(
    const float* __restrict__ inputs, const float* __restrict__ W1,
    const float* __restrict__ b1, const float* __restrict__ W2,
    const float* __restrict__ Wo1, const float* __restrict__ Wo2, const float* __restrict__ Wo3,
    f16* __restrict__ SA, f16* __restrict__ RB, f16* __restrict__ W2p,
    f16* __restrict__ Wo1p, f16* __restrict__ Wo2p, f16* __restrict__ Wo3p,
    int* __restrict__ cnt)
{
  int bid = blockIdx.x;
  int tid = threadIdx.x;
  if (bid < 64) {
    // SA/RB: inputs[512,256] @ W1part[256,512]  (mi = t*2+half; half0->SA, half1->RB+b1)
    int lane = tid & 63, w = tid >> 6;
    int hlf = lane >> 5, l31 = lane & 31;
    int br = bid & 7, bc = (bid >> 3) & 1, mi = bid >> 4;
    int t = mi >> 1, half = mi & 1;
    const float* src = W1 + (size_t)t * 512 * 512 + (size_t)half * 256 * 512;
    f32x16_t acc[2][2];
    #pragma unroll
    for (int rt = 0; rt < 2; rt++)
      #pragma unroll
      for (int ctl = 0; ctl < 2; ctl++)
        #pragma unroll
        for (int r = 0; r < 16; r++) acc[rt][ctl][r] = 0.f;
    for (int kc = 0; kc < 16; kc++) {
      f16x8_t af[2];
      #pragma unroll
      for (int rt = 0; rt < 2; rt++) {
        const float4* p = (const float4*)&inputs[(size_t)(br * 64 + rt * 32 + l31) * 256 + kc * 16 + hlf * 8];
        float4 u0 = p[0], u1 = p[1];
        af[rt] = (f16x8_t){(f16)u0.x, (f16)u0.y, (f16)u0.z, (f16)u0.w,
                           (f16)u1.x, (f16)u1.y, (f16)u1.z, (f16)u1.w};
      }
      #pragma unroll
      for (int ctl = 0; ctl < 2; ctl++) {
        int n  = bc * 256 + (2 * w + ctl) * 32 + l31;
        int k0 = kc * 16 + hlf * 8;
        f16x8_t bfr;
        #pragma unroll
        for (int j = 0; j < 8; j++) bfr[j] = (f16)src[(size_t)(k0 + j) * 512 + n];
        #pragma unroll
        for (int rt = 0; rt < 2; rt++)
          acc[rt][ctl] = __builtin_amdgcn_mfma_f32_32x32x16_f16(af[rt], bfr, acc[rt][ctl], 0, 0, 0);
      }
    }
    f16* dst = (half == 0) ? SA : RB;
    #pragma unroll
    for (int ctl = 0; ctl < 2; ctl++) {
      int col = bc * 256 + (2 * w + ctl) * 32 + l31;
      float bias = (half == 1) ? b1[t * 512 + col] : 0.f;
      #pragma unroll
      for (int rt = 0; rt < 2; rt++)
        #pragma unroll
        for (int r = 0; r < 16; r++) {
          int row = br * 64 + rt * 32 + (r & 3) + 8 * (r >> 2) + 4 * hlf;
          dst[((size_t)(t * 512 + row)) * 512 + col] = (f16)(acc[rt][ctl][r] + bias);
        }
    }
  } else if (bid < 192) {
    int gid  = (bid - 64) * 256 + tid;            // 0..32767
    int lane = gid & 63;
    int ct   = (gid >> 6) & 7;
    int kc   = (gid >> 9) & 31;
    int t    = gid >> 14;
    int n    = ct * 32 + (lane & 31);
    int k0   = kc * 16 + (lane >> 5) * 8;
    const float* src = W2 + (size_t)t * 512 * 256;
    f16x8_t v;
    #pragma unroll
    for (int j = 0; j < 8; j++) v[j] = (f16)src[(size_t)(k0 + j) * 256 + n];
    *(f16x8_t*)(W2p + (size_t)gid * 8) = v;
  } else if (bid < 256) {
    int gid  = (bid - 192) * 256 + tid;           // 0..16383
    int lane = gid & 63;
    int ct   = (gid >> 6) & 15;
    int kc   = gid >> 10;                          // 0..15
    int n    = ct * 32 + (lane & 31);
    int k0   = kc * 16 + (lane >> 5) * 8;
    f16x8_t v;
    #pragma unroll
    for (int j = 0; j < 8; j++) v[j] = (f16)Wo1[(size_t)(k0 + j) * 512 + n];
    *(f16x8_t*)(Wo1p + (size_t)gid * 8) = v;
  } else if (bid < 384) {
    int gid  = (bid - 256) * 256 + tid;           // 0..32767
    int lane = gid & 63;
    int ct   = (gid >> 6) & 15;
    int kc   = gid >> 10;                          // 0..31
    int n    = ct * 32 + (lane & 31);
    int k0   = kc * 16 + (lane >> 5) * 8;
    f16x8_t v;
    #pragma unroll
    for (int j = 0; j < 8; j++) v[j] = (f16)Wo2[(size_t)(k0 + j) * 512 + n];
    *(f16x8_t*)(Wo2p + (size_t)gid * 8) = v;
  } else if (bid < 448) {
    int gid  = (bid - 384) * 256 + tid;           // 0..16383
    int lane = gid & 63;
    int ct   = (gid >> 6) & 7;
    int kc   = gid >> 9;                           // 0..31
    int n    = ct * 32 + (lane & 31);
    int k0   = kc * 16 + (lane >> 5) * 8;
    f16x8_t v;
    #pragma unroll
    for (int j = 0; j < 8; j++) v[j] = (f16)Wo3[(size_t)(k0 + j) * 256 + n];
    *(f16x8_t*)(Wo3p + (size_t)gid * 8) = v;
  } else {
    for (int i = tid; i < 512 * 16; i += 256) cnt[i] = 0;
  }
}

// ---------------- K2: bucketed scatter (no scan) ----------------
__global__ __launch_bounds__(1024) void k_scatter_d(const int* __restrict__ rec,
    const int* __restrict__ send, const float* __restrict__ rel,
    int* __restrict__ cnt, int* __restrict__ ssend, float2* __restrict__ srel)
{
  __shared__ int lh[512];
  __shared__ int lb[512];
  int b = blockIdx.x;
  int e0 = b * (E_N / 64);   // 4088 exactly
  if (threadIdx.x < 512) lh[threadIdx.x] = 0;
  __syncthreads();
  for (int i = threadIdx.x; i < E_N / 64; i += 1024)
    atomicAdd(&lh[rec[e0 + i]], 1);
  __syncthreads();
  if (threadIdx.x < 512) {
    int c = lh[threadIdx.x];
    lb[threadIdx.x] = c ? atomicAdd(&cnt[threadIdx.x * 16], c) : 0;
    lh[threadIdx.x] = 0;
  }
  __syncthreads();
  for (int i = threadIdx.x; i < E_N / 64; i += 1024) {
    int e = e0 + i;
    int r = rec[e];
    int p = (int)((size_t)r * CAP) + lb[r] + atomicAdd(&lh[r], 1);
    ssend[p] = send[e];
    srel[p]  = make_float2(rel[2 * (size_t)e], rel[2 * (size_t)e + 1]);
  }
}

// ---------------- K3: edge MLP + aggregation (R9/R10 structure) ----------------
#define H1S2 264

__global__ __launch_bounds__(512, 4) void k_edges(
    const f16* __restrict__ SA, const f16* __restrict__ RB,
    const f16* __restrict__ W2p, const float* __restrict__ b2,
    const int* __restrict__ ssend, const float2* __restrict__ srel,
    const int* __restrict__ cnt, float* __restrict__ agg)
{
  __shared__ f16   h1[128 * H1S2];
  __shared__ f16   rbs[2][512];
  __shared__ float b2s[2][256];
  __shared__ float aggL[256];
  __shared__ float relv2[2][128][2];
  __shared__ int   sends2[2][128];

  int c    = blockIdx.x;
  int tid  = threadIdx.x;
  int lane = tid & 63;
  int w    = tid >> 6;
  int hlf  = lane >> 5;
  int l31  = lane & 31;
  int q5   = tid & 31;
  int rb0  = tid >> 5;

  if (tid < 128) {
    int t = tid >> 6, qq = tid & 63;
    *(f16x8_t*)&rbs[t][qq * 8] = *(const f16x8_t*)&RB[((size_t)(t * 512 + c)) * 512 + qq * 8];
  }
  if (tid < 256) aggL[tid] = 0.0f;
  { int t = (tid >> 8) & 1, col = tid & 255; b2s[t][col] = b2[t * 256 + col]; }

  int s0 = c * CAP;
  int s1 = s0 + cnt[c * 16];
  int nt = (s1 - s0 + 127) >> 7;

  if (nt > 0 && tid < 128) {
    int pos = s0 + tid;
    if (pos < s1) {
      sends2[0][tid] = ssend[pos];
      float2 rr = srel[pos];
      relv2[0][tid][0] = rr.x;
      relv2[0][tid][1] = rr.y;
    } else {
      sends2[0][tid] = 0; relv2[0][tid][0] = 0.f; relv2[0][tid][1] = 0.f;
    }
  }
  __syncthreads();

  f16x8_t g[8];
  const f16x8_t* SAc = (const f16x8_t*)SA;
  const f16x8_t* Bp  = (const f16x8_t*)W2p;
  f32x16_t acc[4];

  if (nt > 0) {
    #pragma unroll
    for (int j = 0; j < 8; j++)
      g[j] = SAc[(size_t)sends2[0][rb0 + 16 * j] * 64 + q5];
  }

  for (int ph = 0; ph < 4 * nt; ph++) {
    int ti  = ph >> 2;
    int t   = (ph >> 1) & 1;
    int kh  = ph & 1;
    int cb  = ti & 1;
    int nb  = cb ^ 1;
    bool more = (ti + 1 < nt);

    {
      f16x8_t rbq = *(const f16x8_t*)&rbs[t][(kh * 32 + q5) * 8];
      #pragma unroll
      for (int j = 0; j < 8; j++) {
        int row = rb0 + 16 * j;
        f16x8_t hv;
        #pragma unroll
        for (int e = 0; e < 8; e++) {
          f16 v = (f16)(g[j][e] + rbq[e]);
          hv[e] = (v > (f16)0.0f) ? v : (f16)0.0f;
        }
        *(f16x8_t*)&h1[row * H1S2 + q5 * 8] = hv;
      }
    }
    __syncthreads();

    if (t == 0 && kh == 0 && more && tid < 128) {
      int pos = s0 + (ti + 1) * 128 + tid;
      if (pos < s1) {
        sends2[nb][tid] = ssend[pos];
        float2 rr = srel[pos];
        relv2[nb][tid][0] = rr.x;
        relv2[nb][tid][1] = rr.y;
      } else {
        sends2[nb][tid] = 0; relv2[nb][tid][0] = 0.f; relv2[nb][tid][1] = 0.f;
      }
    }

    if (kh == 0) {
      #pragma unroll
      for (int rt = 0; rt < 4; rt++)
        #pragma unroll
        for (int r = 0; r < 16; r++) acc[rt][r] = 0.f;
    }

    f16x8_t bb[2];
    bb[0] = Bp[(size_t)(((t * 32 + kh * 16 + 0) * 8 + w) * 64 + lane)];
    bb[1] = Bp[(size_t)(((t * 32 + kh * 16 + 1) * 8 + w) * 64 + lane)];

    if (kh == 0) {
      #pragma unroll
      for (int j = 0; j < 8; j++)
        g[j] = SAc[(size_t)(t * 512 + sends2[cb][rb0 + 16 * j]) * 64 + 32 + q5];
    } else if (t == 0) {
      #pragma unroll
      for (int j = 0; j < 8; j++)
        g[j] = SAc[(size_t)(512 + sends2[cb][rb0 + 16 * j]) * 64 + q5];
    } else if (more) {
      #pragma unroll
      for (int j = 0; j < 8; j++)
        g[j] = SAc[(size_t)sends2[nb][rb0 + 16 * j] * 64 + q5];
    }

    for (int kc = 0; kc < 16; kc++) {
      int pb = kc & 1;
      #pragma unroll
      for (int rt = 0; rt < 4; rt++) {
        f16x8_t af = *(const f16x8_t*)&h1[(rt * 32 + l31) * H1S2 + kc * 16 + hlf * 8];
        acc[rt] = __builtin_amdgcn_mfma_f32_32x32x16_f16(af, bb[pb], acc[rt], 0, 0, 0);
      }
      if (kc + 2 < 16)
        bb[pb] = Bp[(size_t)(((t * 32 + kh * 16 + kc + 2) * 8 + w) * 64 + lane)];
    }

    if (kh == 1) {
      int col = w * 32 + l31;
      float b2c = b2s[t][col];
      float csum = 0.0f;
      #pragma unroll
      for (int rt = 0; rt < 4; rt++)
        #pragma unroll
        for (int r = 0; r < 16; r++) {
          int row = rt * 32 + (r & 3) + 8 * (r >> 2) + 4 * hlf;
          float v = fmaxf(acc[rt][r] + b2c, 0.0f);
          csum += v * relv2[cb][row][t];
        }
      csum += __shfl_xor(csum, 32, 64);
      if (hlf == 0) aggL[col] += csum;
    }
    __syncthreads();
  }

  if (tid < 256) agg[(size_t)c * 256 + tid] = aggL[tid];
}

// ---------------- K4: fused output MLP (rows are independent; 3 layers in-block) ----------------
#define HOS 520   // LDS row stride (512 + 8)

__global__ __launch_bounds__(512, 1) void k_omlp(const float* __restrict__ agg,
    const f16* __restrict__ Wo1p, const float* __restrict__ bo1,
    const f16* __restrict__ Wo2p, const float* __restrict__ bo2,
    const f16* __restrict__ Wo3p, const float* __restrict__ bo3,
    float* __restrict__ out)
{
  __shared__ f16 hL1[64 * HOS];   // 66560 B
  __shared__ f16 hL2[64 * HOS];   // 66560 B
  int tid = threadIdx.x, lane = tid & 63, w = tid >> 6;   // 8 waves
  int hlf = lane >> 5, l31 = lane & 31;
  int br = blockIdx.x;                                     // 64 rows per block

  // ---- layer 1: h1 = relu(agg[64,256] @ Wo1 + bo1); wave w -> ct 2w,2w+1 ----
  {
    f32x16_t acc[2][2];
    #pragma unroll
    for (int rt = 0; rt < 2; rt++)
      #pragma unroll
      for (int ctl = 0; ctl < 2; ctl++)
        #pragma unroll
        for (int r = 0; r < 16; r++) acc[rt][ctl][r] = 0.f;
    for (int kc = 0; kc < 16; kc++) {
      f16x8_t af[2];
      #pragma unroll
      for (int rt = 0; rt < 2; rt++) {
        const float4* p = (const float4*)&agg[(size_t)(br * 64 + rt * 32 + l31) * 256 + kc * 16 + hlf * 8];
        float4 u0 = p[0], u1 = p[1];
        af[rt] = (f16x8_t){(f16)u0.x, (f16)u0.y, (f16)u0.z, (f16)u0.w,
                           (f16)u1.x, (f16)u1.y, (f16)u1.z, (f16)u1.w};
      }
      #pragma unroll
      for (int ctl = 0; ctl < 2; ctl++) {
        int ct = 2 * w + ctl;
        f16x8_t bfr = *(const f16x8_t*)&Wo1p[((size_t)(kc * 16 + ct) * 64 + lane) * 8];
        #pragma unroll
        for (int rt = 0; rt < 2; rt++)
          acc[rt][ctl] = __builtin_amdgcn_mfma_f32_32x32x16_f16(af[rt], bfr, acc[rt][ctl], 0, 0, 0);
      }
    }
    #pragma unroll
    for (int ctl = 0; ctl < 2; ctl++) {
      int col = (2 * w + ctl) * 32 + l31;
      float bias = bo1[col];
      #pragma unroll
      for (int rt = 0; rt < 2; rt++)
        #pragma unroll
        for (int r = 0; r < 16; r++) {
          int row = rt * 32 + (r & 3) + 8 * (r >> 2) + 4 * hlf;
          hL1[row * HOS + col] = (f16)fmaxf(acc[rt][ctl][r] + bias, 0.f);
        }
    }
  }
  __syncthreads();

  // ---- layer 2: h2 = relu(h1 @ Wo2 + bo2) ----
  {
    f32x16_t acc[2][2];
    #pragma unroll
    for (int rt = 0; rt < 2; rt++)
      #pragma unroll
      for (int ctl = 0; ctl < 2; ctl++)
        #pragma unroll
        for (int r = 0; r < 16; r++) acc[rt][ctl][r] = 0.f;
    for (int kc = 0; kc < 32; kc++) {
      f16x8_t af[2];
      #pragma unroll
      for (int rt = 0; rt < 2; rt++)
        af[rt] = *(const f16x8_t*)&hL1[(rt * 32 + l31) * HOS + kc * 16 + hlf * 8];
      #pragma unroll
      for (int ctl = 0; ctl < 2; ctl++) {
        int ct = 2 * w + ctl;
        f16x8_t bfr = *(const f16x8_t*)&Wo2p[((size_t)(kc * 16 + ct) * 64 + lane) * 8];
        #pragma unroll
        for (int rt = 0; rt < 2; rt++)
          acc[rt][ctl] = __builtin_amdgcn_mfma_f32_32x32x16_f16(af[rt], bfr, acc[rt][ctl], 0, 0, 0);
      }
    }
    #pragma unroll
    for (int ctl = 0; ctl < 2; ctl++) {
      int col = (2 * w + ctl) * 32 + l31;
      float bias = bo2[col];
      #pragma unroll
      for (int rt = 0; rt < 2; rt++)
        #pragma unroll
        for (int r = 0; r < 16; r++) {
          int row = rt * 32 + (r & 3) + 8 * (r >> 2) + 4 * hlf;
          hL2[row * HOS + col] = (f16)fmaxf(acc[rt][ctl][r] + bias, 0.f);
        }
    }
  }
  __syncthreads();

  // ---- layer 3: out = h2 @ Wo3 + bo3; wave w -> ct w (N=256 -> 8 col tiles) ----
  {
    f32x16_t acc[2];
    #pragma unroll
    for (int rt = 0; rt < 2; rt++)
      #pragma unroll
      for (int r = 0; r < 16; r++) acc[rt][r] = 0.f;
    for (int kc = 0; kc < 32; kc++) {
      f16x8_t bfr = *(const f16x8_t*)&Wo3p[((size_t)(kc * 8 + w) * 64 + lane) * 8];
      #pragma unroll
      for (int rt = 0; rt < 2; rt++) {
        f16x8_t af = *(const f16x8_t*)&hL2[(rt * 32 + l31) * HOS + kc * 16 + hlf * 8];
        acc[rt] = __builtin_amdgcn_mfma_f32_32x32x16_f16(af, bfr, acc[rt], 0, 0, 0);
      }
    }
    int col = w * 32 + l31;
    float bias = bo3[col];
    #pragma unroll
    for (int rt = 0; rt < 2; rt++)
      #pragma unroll
      for (int r = 0; r < 16; r++) {
        int row = br * 64 + rt * 32 + (r & 3) + 8 * (r >> 2) + 4 * hlf;
        out[(size_t)row * 256 + col] = acc[rt][r] + bias;
      }
  }
}

// ---------------- launcher ----------------
extern "C" void kernel_launch(void* const* d_in, const int* in_sizes, int n_in,
                              void* d_out, int out_size, void* d_ws, size_t ws_size,
                              hipStream_t stream)
{
  (void)in_sizes; (void)n_in; (void)out_size; (void)ws_size;
  const float* inputs = (const float*)d_in[0];
  const float* rel    = (const float*)d_in[1];
  const float* W1     = (const float*)d_in[2];
  const float* b1     = (const float*)d_in[3];
  const float* W2     = (const float*)d_in[4];
  const float* b2     = (const float*)d_in[5];
  const float* Wo1    = (const float*)d_in[6];
  const float* bo1    = (const float*)d_in[7];
  const float* Wo2    = (const float*)d_in[8];
  const float* bo2    = (const float*)d_in[9];
  const float* Wo3    = (const float*)d_in[10];
  const float* bo3    = (const float*)d_in[11];
  const int* send_idx = (const int*)d_in[12];
  const int* rec_idx  = (const int*)d_in[13];
  float* out = (float*)d_out;

  char* ws = (char*)d_ws;
  f16*    SA    = (f16*)   (ws);                   // 1 MB
  f16*    RB    = (f16*)   (ws + (1024u << 10));   // 1 MB
  f16*    W2p   = (f16*)   (ws + (2048u << 10));   // 512 KB
  float*  agg   = (float*) (ws + (2560u << 10));   // 512 KB
  int*    cnt   = (int*)   (ws + (3072u << 10));   // 32 KB (512 x 16 ints, padded)
  f16*    Wo1p  = (f16*)   (ws + (3136u << 10));   // 256 KB
  f16*    Wo2p  = (f16*)   (ws + (3392u << 10));   // 512 KB
  f16*    Wo3p  = (f16*)   (ws + (3904u << 10));   // 256 KB
  int*    ssend = (int*)   (ws + (4160u << 10));   // 1.5 MB (512*768*4)
  float2* srel  = (float2*)(ws + (5696u << 10));   // 3 MB   (512*768*8) -> total ~8.7 MB

  k_prep_all <<<dim3(449), dim3(256),  0, stream>>>(inputs, W1, b1, W2, Wo1, Wo2, Wo3,
                                                    SA, RB, W2p, Wo1p, Wo2p, Wo3p, cnt);
  k_scatter_d<<<dim3(64),  dim3(1024), 0, stream>>>(rec_idx, send_idx, rel, cnt, ssend, srel);
  k_edges    <<<dim3(512), dim3(512),  0, stream>>>(SA, RB, W2p, b2, ssend, srel, cnt, agg);
  k_omlp     <<<dim3(8),   dim3(512),  0, stream>>>(agg, Wo1p, bo1, Wo2p, bo2, Wo3p, bo3, out);
}